// Round 9
// baseline (451.732 us; speedup 1.0000x reference)
//
#include <hip/hip_runtime.h>
#include <math.h>

#define B_TOTAL 8192
#define C_DIM 62
#define CC (C_DIM * C_DIM)   // 3844 floats
#define EPSV 1e-4f
#define NSWEEP 6
#define WSTRIDE 72           // per-group exchange stride
#define YSTR 9               // Ys stride: gcd(9,32)=1 -> conflict-free writes

// ---------------- Kernel A: M1[b] = w1^T X[b] w1  (62->8) ----------------
// R8 body, wrapped in an nrep loop for profiling visibility. Reps 0..n-2
// write to ws scratch; final rep writes the real M1. Deterministic.
__global__ __launch_bounds__(64, 4) void bimap1_kernel(
    const float* __restrict__ X, const float* __restrict__ w1,
    float* __restrict__ M1, float* __restrict__ wsA, int nrep) {
  __shared__ __align__(16) float w1s[C_DIM * 8];  // 496
  __shared__ float Ys[C_DIM * YSTR];              // padded stride 9
  const int lane = threadIdx.x;
  const int b = blockIdx.x;

#pragma unroll 1
  for (int rep = 0; rep < nrep; ++rep) {
    float* dst = (rep == nrep - 1) ? M1 : (wsA + (size_t)rep * 524288);
    // my X row -> 62 registers (31 x float2, 8B-aligned: 248*c % 8 == 0)
    float xr[C_DIM];
    {
      const float* row = X + (size_t)b * CC + lane * C_DIM;
      if (lane < C_DIM) {
#pragma unroll
        for (int k = 0; k < 31; ++k) {
          float2 t = *(const float2*)(row + 2 * k);
          xr[2 * k] = t.x;
          xr[2 * k + 1] = t.y;
        }
      }
    }
    // w1 -> LDS (32B-aligned rows)
    if (lane < C_DIM) {
      *(float4*)(w1s + lane * 8)     = *(const float4*)(w1 + lane * 8);
      *(float4*)(w1s + lane * 8 + 4) = *(const float4*)(w1 + lane * 8 + 4);
    }
    __syncthreads();

    // Y[c][e] = sum_d X[c][d] * w1[d][e] ; lane c owns row c.
    if (lane < C_DIM) {
      float a0=0.f,a1=0.f,a2=0.f,a3=0.f,a4=0.f,a5=0.f,a6=0.f,a7=0.f;
#pragma unroll
      for (int d = 0; d < C_DIM; ++d) {
        float x = xr[d];
        float4 wA = *(const float4*)(w1s + d * 8);
        float4 wB = *(const float4*)(w1s + d * 8 + 4);
        a0 = fmaf(x, wA.x, a0); a1 = fmaf(x, wA.y, a1);
        a2 = fmaf(x, wA.z, a2); a3 = fmaf(x, wA.w, a3);
        a4 = fmaf(x, wB.x, a4); a5 = fmaf(x, wB.y, a5);
        a6 = fmaf(x, wB.z, a6); a7 = fmaf(x, wB.w, a7);
      }
      float* yr = Ys + lane * YSTR;
      yr[0]=a0; yr[1]=a1; yr[2]=a2; yr[3]=a3;
      yr[4]=a4; yr[5]=a5; yr[6]=a6; yr[7]=a7;
    }
    __syncthreads();

    // M1[a][e] = sum_c w1[c][a] * Y[c][e] ; lane = (a<<3)|e
    {
      const int a = lane >> 3, e = lane & 7;
      float s = 0.f;
#pragma unroll
      for (int c = 0; c < C_DIM; ++c)
        s = fmaf(w1s[c * 8 + a], Ys[c * YSTR + e], s);
      dst[(size_t)b * 64 + lane] = s;
    }
    __syncthreads();   // protect LDS reuse across reps
  }
}

// ---------- cross-lane xor-shuffle: DPP (VALU) for masks 1..3, swizzle else ----------
template<int M> __device__ __forceinline__ float sx(float x) {
  int xi = __builtin_bit_cast(int, x);
  int r;
  if constexpr (M == 1)      r = __builtin_amdgcn_update_dpp(xi, xi, 0xB1, 0xF, 0xF, false);
  else if constexpr (M == 2) r = __builtin_amdgcn_update_dpp(xi, xi, 0x4E, 0xF, 0xF, false);
  else if constexpr (M == 3) r = __builtin_amdgcn_update_dpp(xi, xi, 0x1B, 0xF, 0xF, false);
  else                       r = __builtin_amdgcn_ds_swizzle(xi, (M << 10) | 0x1F);
  return __builtin_bit_cast(float, r);
}

// in-register xor-permute: r[j] <- r[j ^ e]   (24 cndmask)
__device__ __forceinline__ void xperm8(float r[8], const int e) {
  const bool b0 = (e & 1) != 0, b1 = (e & 2) != 0, b2 = (e & 4) != 0;
  float t0[8], t1[8];
#pragma unroll
  for (int j = 0; j < 8; ++j) t0[j] = b0 ? r[j ^ 1] : r[j];
#pragma unroll
  for (int j = 0; j < 8; ++j) t1[j] = b1 ? t0[j ^ 2] : t0[j];
#pragma unroll
  for (int j = 0; j < 8; ++j) r[j] = b2 ? t1[j ^ 4] : t1[j];
}

// ---------- one tournament stage, XOR-relative storage ----------
template<int M>
__device__ __forceinline__ void jstage(float ar[8], float ur[8], const int e) {
  constexpr int HB = (M >= 4) ? 4 : ((M >= 2) ? 2 : 1);
  constexpr int A1 = (M == 1) ? 2 : 1;
  constexpr int A2 = (M <= 3) ? 4 : 2;
  const bool low = (e & HB) == 0;
  float d_oth = sx<M>(ar[0]);
  float o_oth = sx<M>(ar[M]);
  float apq = 0.5f * (ar[M] + o_oth);
  float app = low ? ar[0] : d_oth;
  float aqq = low ? d_oth : ar[0];
  float taun = aqq - app;
  float den = fabsf(taun) + sqrtf(fmaf(taun, taun, 4.f * apq * apq)) + 1e-38f;
  float t = (2.f * apq) * copysignf(1.f, taun) * __builtin_amdgcn_rcpf(den);
  float c = rsqrtf(fmaf(t, t, 1.f));
  float s = t * c;
  float cg[8], sg[8];
  cg[0] = c;  sg[0] = s;
  cg[A1] = sx<A1>(c);  sg[A1] = sx<A1>(s);
  cg[A2] = sx<A2>(c);  sg[A2] = sx<A2>(s);
  cg[A1 ^ A2] = sx<A2>(cg[A1]);  sg[A1 ^ A2] = sx<A2>(sg[A1]);
  float an[8];
#pragma unroll
  for (int d = 0; d < 8; ++d) {
    constexpr int T0 = 0;
    const int rep = (d == T0 || d == A1 || d == A2 || d == (A1 ^ A2)) ? d : (d ^ M);
    const bool flip = (d & HB) != 0;
    float sD = sg[rep];
    float ss = (low != flip) ? -sD : sD;
    an[d] = fmaf(cg[rep], ar[d], ss * ar[d ^ M]);
  }
  float scol = low ? -s : s;
  float aoth[8], uoth[8];
#pragma unroll
  for (int d = 0; d < 8; ++d) aoth[d] = sx<M>(an[d ^ M]);
#pragma unroll
  for (int d = 0; d < 8; ++d) uoth[d] = sx<M>(ur[d ^ M]);
#pragma unroll
  for (int d = 0; d < 8; ++d) ar[d] = fmaf(c, an[d], scol * aoth[d]);
#pragma unroll
  for (int d = 0; d < 8; ++d) ur[d] = fmaf(c, ur[d], scol * uoth[d]);
}

__device__ __forceinline__ void jacobi8rel(float ar[8], float ur[8], const int e) {
#pragma unroll
  for (int i = 0; i < 8; ++i) ur[i] = (i == 0) ? 1.f : 0.f;
#pragma unroll 1
  for (int sweep = 0; sweep < NSWEEP; ++sweep) {
    jstage<1>(ar, ur, e);
    jstage<2>(ar, ur, e);
    jstage<3>(ar, ur, e);
    jstage<4>(ar, ur, e);
    jstage<5>(ar, ur, e);
    jstage<6>(ar, ur, e);
    jstage<7>(ar, ur, e);
  }
}

// ---------------- Kernel B: eig pipeline, 1 wave = 8 batches ----------------
// R8 body wrapped in nrep loop; final rep writes d_out, others ws scratch.
__global__ __launch_bounds__(64) void spd_eig8_kernel(
    const float* __restrict__ M1, const float* __restrict__ w2,
    const float* __restrict__ fc, float* __restrict__ out,
    float* __restrict__ wsB, int nrep) {
  __shared__ __align__(16) float Wbuf[8 * WSTRIDE];
  __shared__ float lwbuf[64];
  __shared__ float w2s[64];
  __shared__ float fcs[128];
  const int tid = threadIdx.x;
  const int e = tid & 7;
  const int g = tid >> 3;
  const int b = blockIdx.x * 8 + g;
  w2s[tid] = w2[tid];
  fcs[tid] = fc[tid];
  fcs[tid + 64] = fc[tid + 64];
  __syncthreads();

#pragma unroll 1
  for (int rep = 0; rep < nrep; ++rep) {
    float* o = (rep == nrep - 1) ? out : (wsB + (size_t)rep * 540672);
    float a[8], u[8], v[8], m2[8];
    float* Wg = &Wbuf[g * WSTRIDE];

    const float4* m4 = (const float4*)(M1 + (size_t)b * 64 + e * 8);
    float4 v0 = m4[0], v1 = m4[1];
    a[0] = v0.x; a[1] = v0.y; a[2] = v0.z; a[3] = v0.w;
    a[4] = v1.x; a[5] = v1.y; a[6] = v1.z; a[7] = v1.w;

    // ---- eig 1 ----
    xperm8(a, e);
    jacobi8rel(a, u, e);
    float lam = a[0];
    float sw = sqrtf(fmaxf(lam, EPSV));
    xperm8(u, e);
#pragma unroll
    for (int j = 0; j < 8; ++j) v[j] = 0.f;
#pragma unroll
    for (int i = 0; i < 8; ++i)
#pragma unroll
      for (int j = 0; j < 8; ++j) v[j] = fmaf(u[i], w2s[i * 8 + j], v[j]);
#pragma unroll
    for (int j = 0; j < 8; ++j) Wg[e * 8 + j] = v[j] * sw;
    __syncthreads();
    {
      float wcol[8];
#pragma unroll
      for (int k = 0; k < 8; ++k) wcol[k] = Wg[k * 8 + e];
#pragma unroll
      for (int i = 0; i < 8; ++i) m2[i] = 0.f;
#pragma unroll
      for (int k = 0; k < 8; ++k) {
        float4 q0 = *(const float4*)&Wg[k * 8 + 0];
        float4 q1 = *(const float4*)&Wg[k * 8 + 4];
        m2[0] = fmaf(q0.x, wcol[k], m2[0]); m2[1] = fmaf(q0.y, wcol[k], m2[1]);
        m2[2] = fmaf(q0.z, wcol[k], m2[2]); m2[3] = fmaf(q0.w, wcol[k], m2[3]);
        m2[4] = fmaf(q1.x, wcol[k], m2[4]); m2[5] = fmaf(q1.y, wcol[k], m2[5]);
        m2[6] = fmaf(q1.z, wcol[k], m2[6]); m2[7] = fmaf(q1.w, wcol[k], m2[7]);
      }
    }
    __syncthreads();

    // ---- eig 2 + fused rec+logm ----
    xperm8(m2, e);
    jacobi8rel(m2, u, e);
    float lw = logf(fmaxf(m2[0], EPSV));
    xperm8(u, e);
#pragma unroll
    for (int i = 0; i < 8; ++i) Wg[e * 8 + i] = u[i];
    lwbuf[g * 8 + e] = lw;
    __syncthreads();
    {
      float mk[8];
#pragma unroll
      for (int k = 0; k < 8; ++k) mk[k] = lwbuf[g * 8 + k] * Wg[k * 8 + e];
      float fcol[8];
#pragma unroll
      for (int i = 0; i < 8; ++i) fcol[i] = 0.f;
#pragma unroll
      for (int k = 0; k < 8; ++k) {
        float4 q0 = *(const float4*)&Wg[k * 8 + 0];
        float4 q1 = *(const float4*)&Wg[k * 8 + 4];
        fcol[0] = fmaf(q0.x, mk[k], fcol[0]); fcol[1] = fmaf(q0.y, mk[k], fcol[1]);
        fcol[2] = fmaf(q0.z, mk[k], fcol[2]); fcol[3] = fmaf(q0.w, mk[k], fcol[3]);
        fcol[4] = fmaf(q1.x, mk[k], fcol[4]); fcol[5] = fmaf(q1.y, mk[k], fcol[5]);
        fcol[6] = fmaf(q1.z, mk[k], fcol[6]); fcol[7] = fmaf(q1.w, mk[k], fcol[7]);
      }
      float l0 = 0.f, l1 = 0.f;
      float* featg = o + 2 * (size_t)B_TOTAL + (size_t)b * 64;
#pragma unroll
      for (int i = 0; i < 8; ++i) {
        featg[i * 8 + e] = fcol[i];
        l0 = fmaf(fcol[i], fcs[(i * 8 + e) * 2 + 0], l0);
        l1 = fmaf(fcol[i], fcs[(i * 8 + e) * 2 + 1], l1);
      }
      l0 += sx<1>(l0); l0 += sx<2>(l0); l0 += sx<4>(l0);
      l1 += sx<1>(l1); l1 += sx<2>(l1); l1 += sx<4>(l1);
      float mx = fmaxf(l0, l1);
      float lse = mx + logf(expf(l0 - mx) + expf(l1 - mx));
      if (e < 2) o[(size_t)b * 2 + e] = (e ? l1 : l0) - lse;
    }
    __syncthreads();   // protect LDS reuse across reps
  }
}

extern "C" void kernel_launch(void* const* d_in, const int* in_sizes, int n_in,
                              void* d_out, int out_size, void* d_ws, size_t ws_size,
                              hipStream_t stream) {
  const float* X  = (const float*)d_in[0];   // [8192,62,62]
  const float* w1 = (const float*)d_in[1];   // [62,8]
  const float* w2 = (const float*)d_in[2];   // [8,8]
  const float* fc = (const float*)d_in[3];   // [64,2]
  float* out = (float*)d_out;                // [8192*2] ++ [8192*64]
  float* M1  = (float*)d_ws;                 // 8192*64 floats = 2 MB
  // probe scratch regions (well within ws): A reps at +8MB, B reps at +64MB
  float* wsA = (float*)((char*)d_ws + (8u  << 20));
  float* wsB = (float*)((char*)d_ws + (64u << 20));

  bimap1_kernel<<<B_TOTAL, 64, 0, stream>>>(X, w1, M1, wsA, 4);
  spd_eig8_kernel<<<B_TOTAL / 8, 64, 0, stream>>>(M1, w2, fc, out, wsB, 10);
}

// Round 10
// 75.117 us; speedup vs baseline: 6.0137x; 6.0137x over previous
//
#include <hip/hip_runtime.h>
#include <math.h>

#define B_TOTAL 8192
#define C_DIM 62
#define CC (C_DIM * C_DIM)   // 3844 floats
#define EPSV 1e-4f
#define NSWEEP 6
#define WSTRIDE 72           // per-group exchange stride
#define YSTR 9               // Ys stride: gcd(9,32)=1 -> conflict-free writes

// ---------------- Kernel A: M1[b] = w1^T X[b] w1  (62->8) ----------------
// One wave per batch; X rows straight to registers (L3-resident input);
// LDS only for w1 broadcasts + Ys exchange. ~11 us, near L3-BW roofline.
__global__ __launch_bounds__(64, 4) void bimap1_kernel(
    const float* __restrict__ X, const float* __restrict__ w1,
    float* __restrict__ M1) {
  __shared__ __align__(16) float w1s[C_DIM * 8];  // 496
  __shared__ float Ys[C_DIM * YSTR];              // padded stride 9
  const int lane = threadIdx.x;
  const int b = blockIdx.x;

  // my X row -> 62 registers (31 x float2, always 8B-aligned: 248*c % 8 == 0)
  float xr[C_DIM];
  {
    const float* row = X + (size_t)b * CC + lane * C_DIM;
    if (lane < C_DIM) {
#pragma unroll
      for (int k = 0; k < 31; ++k) {
        float2 t = *(const float2*)(row + 2 * k);
        xr[2 * k] = t.x;
        xr[2 * k + 1] = t.y;
      }
    }
  }
  // w1 -> LDS (32B-aligned rows)
  if (lane < C_DIM) {
    *(float4*)(w1s + lane * 8)     = *(const float4*)(w1 + lane * 8);
    *(float4*)(w1s + lane * 8 + 4) = *(const float4*)(w1 + lane * 8 + 4);
  }
  __syncthreads();

  // Y[c][e] = sum_d X[c][d] * w1[d][e] ; lane c owns row c.
  if (lane < C_DIM) {
    float a0=0.f,a1=0.f,a2=0.f,a3=0.f,a4=0.f,a5=0.f,a6=0.f,a7=0.f;
#pragma unroll
    for (int d = 0; d < C_DIM; ++d) {
      float x = xr[d];
      float4 wA = *(const float4*)(w1s + d * 8);
      float4 wB = *(const float4*)(w1s + d * 8 + 4);
      a0 = fmaf(x, wA.x, a0); a1 = fmaf(x, wA.y, a1);
      a2 = fmaf(x, wA.z, a2); a3 = fmaf(x, wA.w, a3);
      a4 = fmaf(x, wB.x, a4); a5 = fmaf(x, wB.y, a5);
      a6 = fmaf(x, wB.z, a6); a7 = fmaf(x, wB.w, a7);
    }
    float* yr = Ys + lane * YSTR;
    yr[0]=a0; yr[1]=a1; yr[2]=a2; yr[3]=a3;
    yr[4]=a4; yr[5]=a5; yr[6]=a6; yr[7]=a7;
  }
  __syncthreads();

  // M1[a][e] = sum_c w1[c][a] * Y[c][e] ; lane = (a<<3)|e
  {
    const int a = lane >> 3, e = lane & 7;
    float s = 0.f;
#pragma unroll
    for (int c = 0; c < C_DIM; ++c)
      s = fmaf(w1s[c * 8 + a], Ys[c * YSTR + e], s);
    M1[(size_t)b * 64 + lane] = s;
  }
}

// ---------- cross-lane xor-shuffle within 8-lane groups: PURE DPP ----------
// masks 1..3: quad_perm. mask 7: row_half_mirror (0x141). masks 4..6:
// row_half_mirror composed with quad_perm(7^M). All VALU-pipe, ~2cyc each,
// zero LDS traffic -> no lgkmcnt stalls inside the serial Jacobi chain.
template<int M> __device__ __forceinline__ float sx(float x) {
  int xi = __builtin_bit_cast(int, x);
  int r;
  if constexpr (M == 1)      r = __builtin_amdgcn_update_dpp(xi, xi, 0xB1, 0xF, 0xF, false);
  else if constexpr (M == 2) r = __builtin_amdgcn_update_dpp(xi, xi, 0x4E, 0xF, 0xF, false);
  else if constexpr (M == 3) r = __builtin_amdgcn_update_dpp(xi, xi, 0x1B, 0xF, 0xF, false);
  else if constexpr (M == 7) r = __builtin_amdgcn_update_dpp(xi, xi, 0x141, 0xF, 0xF, false);
  else {
    int t = __builtin_amdgcn_update_dpp(xi, xi, 0x141, 0xF, 0xF, false);  // xor 7
    constexpr int Q = 7 ^ M;  // 3,2,1
    constexpr int ctrl = (Q == 1) ? 0xB1 : (Q == 2) ? 0x4E : 0x1B;
    r = __builtin_amdgcn_update_dpp(t, t, ctrl, 0xF, 0xF, false);
  }
  return __builtin_bit_cast(float, r);
}

// in-register xor-permute: r[j] <- r[j ^ e]   (24 cndmask)
__device__ __forceinline__ void xperm8(float r[8], const int e) {
  const bool b0 = (e & 1) != 0, b1 = (e & 2) != 0, b2 = (e & 4) != 0;
  float t0[8], t1[8];
#pragma unroll
  for (int j = 0; j < 8; ++j) t0[j] = b0 ? r[j ^ 1] : r[j];
#pragma unroll
  for (int j = 0; j < 8; ++j) t1[j] = b1 ? t0[j ^ 2] : t0[j];
#pragma unroll
  for (int j = 0; j < 8; ++j) r[j] = b2 ? t1[j ^ 4] : t1[j];
}

// ---------- one tournament stage, XOR-relative storage ----------
// lane e stores ar[d] = A[e^d][e], ur[d] = U[e^d][e]. Pairs (i, i^M).
template<int M>
__device__ __forceinline__ void jstage(float ar[8], float ur[8], const int e) {
  constexpr int HB = (M >= 4) ? 4 : ((M >= 2) ? 2 : 1);  // highest bit of M
  constexpr int A1 = (M == 1) ? 2 : 1;                   // transversal masks
  constexpr int A2 = (M <= 3) ? 4 : 2;
  const bool low = (e & HB) == 0;      // is e the min of its pair
  float d_oth = sx<M>(ar[0]);
  float o_oth = sx<M>(ar[M]);
  float apq = 0.5f * (ar[M] + o_oth);  // symmetrized: both lanes identical
  float app = low ? ar[0] : d_oth;
  float aqq = low ? d_oth : ar[0];
  float taun = aqq - app;
  float den = fabsf(taun) + sqrtf(fmaf(taun, taun, 4.f * apq * apq)) + 1e-38f;
  float t = (2.f * apq) * copysignf(1.f, taun) * __builtin_amdgcn_rcpf(den);
  float c = rsqrtf(fmaf(t, t, 1.f));
  float s = t * c;                      // canonical (p=min, q=max) rotation
  // allgather canonical (c,s) of all 4 pairs into transversal slots
  float cg[8], sg[8];
  cg[0] = c;  sg[0] = s;
  cg[A1] = sx<A1>(c);  sg[A1] = sx<A1>(s);
  cg[A2] = sx<A2>(c);  sg[A2] = sx<A2>(s);
  cg[A1 ^ A2] = sx<A2>(cg[A1]);  sg[A1 ^ A2] = sx<A2>(sg[A1]);
  // row update: A <- J^T A
  float an[8];
#pragma unroll
  for (int d = 0; d < 8; ++d) {
    constexpr int T0 = 0;
    const int rep = (d == T0 || d == A1 || d == A2 || d == (A1 ^ A2)) ? d : (d ^ M);
    const bool flip = (d & HB) != 0;
    float sD = sg[rep];
    float ss = (low != flip) ? -sD : sD;
    an[d] = fmaf(cg[rep], ar[d], ss * ar[d ^ M]);
  }
  // col update: A <- A J ; U <- U J
  float scol = low ? -s : s;
  float aoth[8], uoth[8];
#pragma unroll
  for (int d = 0; d < 8; ++d) aoth[d] = sx<M>(an[d ^ M]);
#pragma unroll
  for (int d = 0; d < 8; ++d) uoth[d] = sx<M>(ur[d ^ M]);
#pragma unroll
  for (int d = 0; d < 8; ++d) ar[d] = fmaf(c, an[d], scol * aoth[d]);
#pragma unroll
  for (int d = 0; d < 8; ++d) ur[d] = fmaf(c, ur[d], scol * uoth[d]);
}

__device__ __forceinline__ void jacobi8rel(float ar[8], float ur[8], const int e) {
#pragma unroll
  for (int i = 0; i < 8; ++i) ur[i] = (i == 0) ? 1.f : 0.f;  // identity (relative)
#pragma unroll 1
  for (int sweep = 0; sweep < NSWEEP; ++sweep) {
    jstage<1>(ar, ur, e);
    jstage<2>(ar, ur, e);
    jstage<3>(ar, ur, e);
    jstage<4>(ar, ur, e);
    jstage<5>(ar, ur, e);
    jstage<6>(ar, ur, e);
    jstage<7>(ar, ur, e);
  }
}

// ---------------- Kernel B: eig pipeline, 1 wave = 8 batches ----------------
__global__ __launch_bounds__(64) void spd_eig8_kernel(
    const float* __restrict__ M1, const float* __restrict__ w2,
    const float* __restrict__ fc, float* __restrict__ out) {
  __shared__ __align__(16) float Wbuf[8 * WSTRIDE];
  __shared__ float lwbuf[64];
  __shared__ float w2s[64];
  __shared__ float fcs[128];
  const int tid = threadIdx.x;      // 0..63
  const int e = tid & 7;
  const int g = tid >> 3;           // 0..7, batch group
  const int b = blockIdx.x * 8 + g;
  w2s[tid] = w2[tid];
  fcs[tid] = fc[tid];
  fcs[tid + 64] = fc[tid + 64];

  float a[8], u[8], v[8], m2[8];
  float* Wg = &Wbuf[g * WSTRIDE];

  // load row e of symmetric M1 (= column e); coalesced 2KB per block
  const float4* m4 = (const float4*)(M1 + (size_t)b * 64 + e * 8);
  float4 v0 = m4[0], v1 = m4[1];
  a[0] = v0.x; a[1] = v0.y; a[2] = v0.z; a[3] = v0.w;
  a[4] = v1.x; a[5] = v1.y; a[6] = v1.z; a[7] = v1.w;
  __syncthreads();  // w2s/fcs ready (intra-wave: cheap)

  // ---- eig 1 ----
  xperm8(a, e);                 // absolute row -> relative column
  jacobi8rel(a, u, e);
  float lam = a[0];             // own eigenvalue (rel slot 0)
  float sw = sqrtf(fmaxf(lam, EPSV));
  xperm8(u, e);                 // u[i] = U[i][e] absolute
  // row e of V = U^T w2, scaled by sqrt(clamped eig)
#pragma unroll
  for (int j = 0; j < 8; ++j) v[j] = 0.f;
#pragma unroll
  for (int i = 0; i < 8; ++i)
#pragma unroll
    for (int j = 0; j < 8; ++j) v[j] = fmaf(u[i], w2s[i * 8 + j], v[j]);
#pragma unroll
  for (int j = 0; j < 8; ++j) Wg[e * 8 + j] = v[j] * sw;
  __syncthreads();
  // M2 column e: m2[i] = sum_k W[k][i] * W[k][e]
  {
    float wcol[8];
#pragma unroll
    for (int k = 0; k < 8; ++k) wcol[k] = Wg[k * 8 + e];
#pragma unroll
    for (int i = 0; i < 8; ++i) m2[i] = 0.f;
#pragma unroll
    for (int k = 0; k < 8; ++k) {
      float4 q0 = *(const float4*)&Wg[k * 8 + 0];
      float4 q1 = *(const float4*)&Wg[k * 8 + 4];
      m2[0] = fmaf(q0.x, wcol[k], m2[0]); m2[1] = fmaf(q0.y, wcol[k], m2[1]);
      m2[2] = fmaf(q0.z, wcol[k], m2[2]); m2[3] = fmaf(q0.w, wcol[k], m2[3]);
      m2[4] = fmaf(q1.x, wcol[k], m2[4]); m2[5] = fmaf(q1.y, wcol[k], m2[5]);
      m2[6] = fmaf(q1.z, wcol[k], m2[6]); m2[7] = fmaf(q1.w, wcol[k], m2[7]);
    }
  }
  __syncthreads();  // Wbuf reads done before reuse

  // ---- eig 2 + fused rec+logm ----
  xperm8(m2, e);
  jacobi8rel(m2, u, e);
  float lw = logf(fmaxf(m2[0], EPSV));
  xperm8(u, e);                 // absolute again
#pragma unroll
  for (int i = 0; i < 8; ++i) Wg[e * 8 + i] = u[i];
  lwbuf[g * 8 + e] = lw;
  __syncthreads();
  // feat column e: fcol[i] = sum_k lw_k * T[k][i] * T[k][e]
  {
    float mk[8];
#pragma unroll
    for (int k = 0; k < 8; ++k) mk[k] = lwbuf[g * 8 + k] * Wg[k * 8 + e];
    float fcol[8];
#pragma unroll
    for (int i = 0; i < 8; ++i) fcol[i] = 0.f;
#pragma unroll
    for (int k = 0; k < 8; ++k) {
      float4 q0 = *(const float4*)&Wg[k * 8 + 0];
      float4 q1 = *(const float4*)&Wg[k * 8 + 4];
      fcol[0] = fmaf(q0.x, mk[k], fcol[0]); fcol[1] = fmaf(q0.y, mk[k], fcol[1]);
      fcol[2] = fmaf(q0.z, mk[k], fcol[2]); fcol[3] = fmaf(q0.w, mk[k], fcol[3]);
      fcol[4] = fmaf(q1.x, mk[k], fcol[4]); fcol[5] = fmaf(q1.y, mk[k], fcol[5]);
      fcol[6] = fmaf(q1.z, mk[k], fcol[6]); fcol[7] = fmaf(q1.w, mk[k], fcol[7]);
    }
    float l0 = 0.f, l1 = 0.f;
    float* featg = out + 2 * (size_t)B_TOTAL + (size_t)b * 64;
#pragma unroll
    for (int i = 0; i < 8; ++i) {
      featg[i * 8 + e] = fcol[i];
      l0 = fmaf(fcol[i], fcs[(i * 8 + e) * 2 + 0], l0);
      l1 = fmaf(fcol[i], fcs[(i * 8 + e) * 2 + 1], l1);
    }
    l0 += sx<1>(l0); l0 += sx<2>(l0); l0 += sx<4>(l0);
    l1 += sx<1>(l1); l1 += sx<2>(l1); l1 += sx<4>(l1);
    float mx = fmaxf(l0, l1);
    float lse = mx + logf(expf(l0 - mx) + expf(l1 - mx));
    if (e < 2) out[(size_t)b * 2 + e] = (e ? l1 : l0) - lse;
  }
}

extern "C" void kernel_launch(void* const* d_in, const int* in_sizes, int n_in,
                              void* d_out, int out_size, void* d_ws, size_t ws_size,
                              hipStream_t stream) {
  const float* X  = (const float*)d_in[0];   // [8192,62,62]
  const float* w1 = (const float*)d_in[1];   // [62,8]
  const float* w2 = (const float*)d_in[2];   // [8,8]
  const float* fc = (const float*)d_in[3];   // [64,2]
  float* out = (float*)d_out;                // [8192*2] ++ [8192*64]
  float* M1 = (float*)d_ws;                  // 8192*64 floats = 2 MB

  bimap1_kernel<<<B_TOTAL, 64, 0, stream>>>(X, w1, M1);
  spd_eig8_kernel<<<B_TOTAL / 8, 64, 0, stream>>>(M1, w2, fc, out);
}

// Round 11
// 56.732 us; speedup vs baseline: 7.9626x; 1.3241x over previous
//
#include <hip/hip_runtime.h>
#include <math.h>

#define B_TOTAL 8192
#define C_DIM 62
#define CC (C_DIM * C_DIM)   // 3844 floats
#define EPSV 1e-4f
#define NSWEEP 5
#define WSTRIDE 72           // per-group exchange stride
#define YSTR 9               // Ys stride: gcd(9,32)=1 -> conflict-free writes

// ---------- cross-lane xor-shuffle: DPP (VALU) for masks 1..3, swizzle 4..7 ----------
// (R8 hybrid — all-DPP for masks 4..6 measured ~7us slower in R10.)
template<int M> __device__ __forceinline__ float sx(float x) {
  int xi = __builtin_bit_cast(int, x);
  int r;
  if constexpr (M == 1)      r = __builtin_amdgcn_update_dpp(xi, xi, 0xB1, 0xF, 0xF, false);
  else if constexpr (M == 2) r = __builtin_amdgcn_update_dpp(xi, xi, 0x4E, 0xF, 0xF, false);
  else if constexpr (M == 3) r = __builtin_amdgcn_update_dpp(xi, xi, 0x1B, 0xF, 0xF, false);
  else                       r = __builtin_amdgcn_ds_swizzle(xi, (M << 10) | 0x1F);
  return __builtin_bit_cast(float, r);
}

// in-register xor-permute: r[j] <- r[j ^ e]   (24 cndmask)
__device__ __forceinline__ void xperm8(float r[8], const int e) {
  const bool b0 = (e & 1) != 0, b1 = (e & 2) != 0, b2 = (e & 4) != 0;
  float t0[8], t1[8];
#pragma unroll
  for (int j = 0; j < 8; ++j) t0[j] = b0 ? r[j ^ 1] : r[j];
#pragma unroll
  for (int j = 0; j < 8; ++j) t1[j] = b1 ? t0[j ^ 2] : t0[j];
#pragma unroll
  for (int j = 0; j < 8; ++j) r[j] = b2 ? t1[j ^ 4] : t1[j];
}

// ---------- one tournament stage, XOR-relative storage ----------
// lane e stores ar[d] = A[e^d][e], ur[d] = U[e^d][e]. Pairs (i, i^M).
template<int M>
__device__ __forceinline__ void jstage(float ar[8], float ur[8], const int e) {
  constexpr int HB = (M >= 4) ? 4 : ((M >= 2) ? 2 : 1);  // highest bit of M
  constexpr int A1 = (M == 1) ? 2 : 1;                   // transversal masks
  constexpr int A2 = (M <= 3) ? 4 : 2;
  const bool low = (e & HB) == 0;      // is e the min of its pair
  float d_oth = sx<M>(ar[0]);
  float o_oth = sx<M>(ar[M]);
  float apq = 0.5f * (ar[M] + o_oth);  // symmetrized: both lanes identical
  float app = low ? ar[0] : d_oth;
  float aqq = low ? d_oth : ar[0];
  float taun = aqq - app;
  float den = fabsf(taun) + sqrtf(fmaf(taun, taun, 4.f * apq * apq)) + 1e-38f;
  float t = (2.f * apq) * copysignf(1.f, taun) * __builtin_amdgcn_rcpf(den);
  float c = rsqrtf(fmaf(t, t, 1.f));
  float s = t * c;                      // canonical (p=min, q=max) rotation
  // allgather canonical (c,s) of all 4 pairs into transversal slots
  float cg[8], sg[8];
  cg[0] = c;  sg[0] = s;
  cg[A1] = sx<A1>(c);  sg[A1] = sx<A1>(s);
  cg[A2] = sx<A2>(c);  sg[A2] = sx<A2>(s);
  cg[A1 ^ A2] = sx<A2>(cg[A1]);  sg[A1 ^ A2] = sx<A2>(sg[A1]);
  // row update: A <- J^T A
  float an[8];
#pragma unroll
  for (int d = 0; d < 8; ++d) {
    constexpr int T0 = 0;
    const int rep = (d == T0 || d == A1 || d == A2 || d == (A1 ^ A2)) ? d : (d ^ M);
    const bool flip = (d & HB) != 0;
    float sD = sg[rep];
    float ss = (low != flip) ? -sD : sD;
    an[d] = fmaf(cg[rep], ar[d], ss * ar[d ^ M]);
  }
  // col update: A <- A J ; U <- U J
  float scol = low ? -s : s;
  float aoth[8], uoth[8];
#pragma unroll
  for (int d = 0; d < 8; ++d) aoth[d] = sx<M>(an[d ^ M]);
#pragma unroll
  for (int d = 0; d < 8; ++d) uoth[d] = sx<M>(ur[d ^ M]);
#pragma unroll
  for (int d = 0; d < 8; ++d) ar[d] = fmaf(c, an[d], scol * aoth[d]);
#pragma unroll
  for (int d = 0; d < 8; ++d) ur[d] = fmaf(c, ur[d], scol * uoth[d]);
}

__device__ __forceinline__ void jacobi8rel(float ar[8], float ur[8], const int e) {
#pragma unroll
  for (int i = 0; i < 8; ++i) ur[i] = (i == 0) ? 1.f : 0.f;  // identity (relative)
#pragma unroll 1
  for (int sweep = 0; sweep < NSWEEP; ++sweep) {
    jstage<1>(ar, ur, e);
    jstage<2>(ar, ur, e);
    jstage<3>(ar, ur, e);
    jstage<4>(ar, ur, e);
    jstage<5>(ar, ur, e);
    jstage<6>(ar, ur, e);
    jstage<7>(ar, ur, e);
  }
}

// ---------------- fused kernel: 1 wave = 8 batches, A phase then B phase ----------------
__global__ __launch_bounds__(64) void spdnet_kernel(
    const float* __restrict__ X, const float* __restrict__ w1,
    const float* __restrict__ w2, const float* __restrict__ fc,
    float* __restrict__ out) {
  __shared__ __align__(16) float w1s[C_DIM * 8];  // 496
  __shared__ float Ys[C_DIM * YSTR];              // padded stride 9
  __shared__ float M1s[8 * 64];                   // 8 batches' M1
  __shared__ __align__(16) float Wbuf[8 * WSTRIDE];
  __shared__ float lwbuf[64];
  __shared__ float w2s[64];
  __shared__ float fcs[128];
  const int lane = threadIdx.x;
  const int b0 = blockIdx.x * 8;

  w2s[lane] = w2[lane];
  fcs[lane] = fc[lane];
  fcs[lane + 64] = fc[lane + 64];
  if (lane < C_DIM) {
    *(float4*)(w1s + lane * 8)     = *(const float4*)(w1 + lane * 8);
    *(float4*)(w1s + lane * 8 + 4) = *(const float4*)(w1 + lane * 8 + 4);
  }
  __syncthreads();

  // ---- A phase: M1[g] = w1^T X[b0+g] w1, g = 0..7 serial, per-lane rows ----
#pragma unroll 1
  for (int g = 0; g < 8; ++g) {
    if (lane < C_DIM) {
      // my X row -> registers (31 x float2, 8B-aligned: 248*c % 8 == 0)
      float xr[C_DIM];
      const float* row = X + (size_t)(b0 + g) * CC + lane * C_DIM;
#pragma unroll
      for (int k = 0; k < 31; ++k) {
        float2 t = *(const float2*)(row + 2 * k);
        xr[2 * k] = t.x;
        xr[2 * k + 1] = t.y;
      }
      // Y[c][e] = sum_d X[c][d] * w1[d][e] ; w1s reads wave-uniform broadcast
      float a0=0.f,a1=0.f,a2=0.f,a3=0.f,a4=0.f,a5=0.f,a6=0.f,a7=0.f;
#pragma unroll
      for (int d = 0; d < C_DIM; ++d) {
        float x = xr[d];
        float4 wA = *(const float4*)(w1s + d * 8);
        float4 wB = *(const float4*)(w1s + d * 8 + 4);
        a0 = fmaf(x, wA.x, a0); a1 = fmaf(x, wA.y, a1);
        a2 = fmaf(x, wA.z, a2); a3 = fmaf(x, wA.w, a3);
        a4 = fmaf(x, wB.x, a4); a5 = fmaf(x, wB.y, a5);
        a6 = fmaf(x, wB.z, a6); a7 = fmaf(x, wB.w, a7);
      }
      float* yr = Ys + lane * YSTR;
      yr[0]=a0; yr[1]=a1; yr[2]=a2; yr[3]=a3;
      yr[4]=a4; yr[5]=a5; yr[6]=a6; yr[7]=a7;
    }
    __syncthreads();
    // M1[a][e] = sum_c w1[c][a] * Y[c][e] ; lane = (a<<3)|e
    {
      const int a = lane >> 3, e = lane & 7;
      float s = 0.f;
#pragma unroll
      for (int c = 0; c < C_DIM; ++c)
        s = fmaf(w1s[c * 8 + a], Ys[c * YSTR + e], s);
      M1s[g * 64 + lane] = s;
    }
    __syncthreads();
  }

  // ---- B phase: eig pipeline, 8 lanes per batch ----
  const int e = lane & 7;
  const int g = lane >> 3;
  float a[8], u[8], v[8], m2[8];
  float* Wg = &Wbuf[g * WSTRIDE];

  // row e of symmetric M1 (= column e) from LDS
#pragma unroll
  for (int j = 0; j < 8; ++j) a[j] = M1s[g * 64 + e * 8 + j];

  // ---- eig 1 ----
  xperm8(a, e);                 // absolute row -> relative column
  jacobi8rel(a, u, e);
  float lam = a[0];             // own eigenvalue (rel slot 0)
  float sw = sqrtf(fmaxf(lam, EPSV));
  xperm8(u, e);                 // u[i] = U[i][e] absolute
  // row e of V = U^T w2, scaled by sqrt(clamped eig)
#pragma unroll
  for (int j = 0; j < 8; ++j) v[j] = 0.f;
#pragma unroll
  for (int i = 0; i < 8; ++i)
#pragma unroll
    for (int j = 0; j < 8; ++j) v[j] = fmaf(u[i], w2s[i * 8 + j], v[j]);
#pragma unroll
  for (int j = 0; j < 8; ++j) Wg[e * 8 + j] = v[j] * sw;
  __syncthreads();
  // M2 column e: m2[i] = sum_k W[k][i] * W[k][e]
  {
    float wcol[8];
#pragma unroll
    for (int k = 0; k < 8; ++k) wcol[k] = Wg[k * 8 + e];
#pragma unroll
    for (int i = 0; i < 8; ++i) m2[i] = 0.f;
#pragma unroll
    for (int k = 0; k < 8; ++k) {
      float4 q0 = *(const float4*)&Wg[k * 8 + 0];
      float4 q1 = *(const float4*)&Wg[k * 8 + 4];
      m2[0] = fmaf(q0.x, wcol[k], m2[0]); m2[1] = fmaf(q0.y, wcol[k], m2[1]);
      m2[2] = fmaf(q0.z, wcol[k], m2[2]); m2[3] = fmaf(q0.w, wcol[k], m2[3]);
      m2[4] = fmaf(q1.x, wcol[k], m2[4]); m2[5] = fmaf(q1.y, wcol[k], m2[5]);
      m2[6] = fmaf(q1.z, wcol[k], m2[6]); m2[7] = fmaf(q1.w, wcol[k], m2[7]);
    }
  }
  __syncthreads();  // Wbuf reads done before reuse

  // ---- eig 2 + fused rec+logm ----
  xperm8(m2, e);
  jacobi8rel(m2, u, e);
  float lw = logf(fmaxf(m2[0], EPSV));
  xperm8(u, e);                 // absolute again
#pragma unroll
  for (int i = 0; i < 8; ++i) Wg[e * 8 + i] = u[i];
  lwbuf[g * 8 + e] = lw;
  __syncthreads();
  // feat column e: fcol[i] = sum_k lw_k * T[k][i] * T[k][e]
  {
    float mk[8];
#pragma unroll
    for (int k = 0; k < 8; ++k) mk[k] = lwbuf[g * 8 + k] * Wg[k * 8 + e];
    float fcol[8];
#pragma unroll
    for (int i = 0; i < 8; ++i) fcol[i] = 0.f;
#pragma unroll
    for (int k = 0; k < 8; ++k) {
      float4 q0 = *(const float4*)&Wg[k * 8 + 0];
      float4 q1 = *(const float4*)&Wg[k * 8 + 4];
      fcol[0] = fmaf(q0.x, mk[k], fcol[0]); fcol[1] = fmaf(q0.y, mk[k], fcol[1]);
      fcol[2] = fmaf(q0.z, mk[k], fcol[2]); fcol[3] = fmaf(q0.w, mk[k], fcol[3]);
      fcol[4] = fmaf(q1.x, mk[k], fcol[4]); fcol[5] = fmaf(q1.y, mk[k], fcol[5]);
      fcol[6] = fmaf(q1.z, mk[k], fcol[6]); fcol[7] = fmaf(q1.w, mk[k], fcol[7]);
    }
    float l0 = 0.f, l1 = 0.f;
    const int b = b0 + g;
    float* featg = out + 2 * (size_t)B_TOTAL + (size_t)b * 64;
#pragma unroll
    for (int i = 0; i < 8; ++i) {
      featg[i * 8 + e] = fcol[i];
      l0 = fmaf(fcol[i], fcs[(i * 8 + e) * 2 + 0], l0);
      l1 = fmaf(fcol[i], fcs[(i * 8 + e) * 2 + 1], l1);
    }
    l0 += sx<1>(l0); l0 += sx<2>(l0); l0 += sx<4>(l0);
    l1 += sx<1>(l1); l1 += sx<2>(l1); l1 += sx<4>(l1);
    float mx = fmaxf(l0, l1);
    float lse = mx + logf(expf(l0 - mx) + expf(l1 - mx));
    if (e < 2) out[(size_t)b * 2 + e] = (e ? l1 : l0) - lse;
  }
}

extern "C" void kernel_launch(void* const* d_in, const int* in_sizes, int n_in,
                              void* d_out, int out_size, void* d_ws, size_t ws_size,
                              hipStream_t stream) {
  const float* X  = (const float*)d_in[0];   // [8192,62,62]
  const float* w1 = (const float*)d_in[1];   // [62,8]
  const float* w2 = (const float*)d_in[2];   // [8,8]
  const float* fc = (const float*)d_in[3];   // [64,2]
  float* out = (float*)d_out;                // [8192*2] ++ [8192*64]

  spdnet_kernel<<<B_TOTAL / 8, 64, 0, stream>>>(X, w1, w2, fc, out);
}

// Round 12
// 56.592 us; speedup vs baseline: 7.9822x; 1.0025x over previous
//
#include <hip/hip_runtime.h>
#include <math.h>

#define B_TOTAL 8192
#define C_DIM 62
#define CC (C_DIM * C_DIM)   // 3844 floats
#define EPSV 1e-4f
#define NSWEEP 5
#define WSTRIDE 72           // per-group exchange stride
#define YSTR 9               // Ys stride: gcd(9,32)=1 -> conflict-free writes

// ---------- cross-lane xor-shuffle: DPP (VALU) for masks 1..3, swizzle 4..7 ----------
template<int M> __device__ __forceinline__ float sx(float x) {
  int xi = __builtin_bit_cast(int, x);
  int r;
  if constexpr (M == 1)      r = __builtin_amdgcn_update_dpp(xi, xi, 0xB1, 0xF, 0xF, false);
  else if constexpr (M == 2) r = __builtin_amdgcn_update_dpp(xi, xi, 0x4E, 0xF, 0xF, false);
  else if constexpr (M == 3) r = __builtin_amdgcn_update_dpp(xi, xi, 0x1B, 0xF, 0xF, false);
  else                       r = __builtin_amdgcn_ds_swizzle(xi, (M << 10) | 0x1F);
  return __builtin_bit_cast(float, r);
}

// in-register xor-permute: r[j] <- r[j ^ e]   (24 cndmask)
__device__ __forceinline__ void xperm8(float r[8], const int e) {
  const bool b0 = (e & 1) != 0, b1 = (e & 2) != 0, b2 = (e & 4) != 0;
  float t0[8], t1[8];
#pragma unroll
  for (int j = 0; j < 8; ++j) t0[j] = b0 ? r[j ^ 1] : r[j];
#pragma unroll
  for (int j = 0; j < 8; ++j) t1[j] = b1 ? t0[j ^ 2] : t0[j];
#pragma unroll
  for (int j = 0; j < 8; ++j) r[j] = b2 ? t1[j ^ 4] : t1[j];
}

// ---------- one tournament stage, XOR-relative storage ----------
// lane e stores ar[d] = A[e^d][e]  and  pr[d] = P[e^d][e] where P = U^T.
// A needs row+col update (col = cross-lane); P needs ONLY the row update
// (lane-local, same (c,s) slots as A's row update) -> zero shuffles for U.
template<int M>
__device__ __forceinline__ void jstage(float ar[8], float pr[8], const int e) {
  constexpr int HB = (M >= 4) ? 4 : ((M >= 2) ? 2 : 1);  // highest bit of M
  constexpr int A1 = (M == 1) ? 2 : 1;                   // transversal masks
  constexpr int A2 = (M <= 3) ? 4 : 2;
  const bool low = (e & HB) == 0;      // is e the min of its pair
  float d_oth = sx<M>(ar[0]);
  float o_oth = sx<M>(ar[M]);
  float apq = 0.5f * (ar[M] + o_oth);  // symmetrized: both lanes identical
  float app = low ? ar[0] : d_oth;
  float aqq = low ? d_oth : ar[0];
  float taun = aqq - app;
  float den = fabsf(taun) + sqrtf(fmaf(taun, taun, 4.f * apq * apq)) + 1e-38f;
  float t = (2.f * apq) * copysignf(1.f, taun) * __builtin_amdgcn_rcpf(den);
  float c = rsqrtf(fmaf(t, t, 1.f));
  float s = t * c;                      // canonical (p=min, q=max) rotation
  // allgather canonical (c,s) of all 4 pairs into transversal slots
  float cg[8], sg[8];
  cg[0] = c;  sg[0] = s;
  cg[A1] = sx<A1>(c);  sg[A1] = sx<A1>(s);
  cg[A2] = sx<A2>(c);  sg[A2] = sx<A2>(s);
  cg[A1 ^ A2] = sx<A2>(cg[A1]);  sg[A1 ^ A2] = sx<A2>(sg[A1]);
  // row update: A <- J^T A  and  P <- J^T P  (same pairs, same coeffs)
  float an[8], pn[8];
#pragma unroll
  for (int d = 0; d < 8; ++d) {
    constexpr int T0 = 0;
    const int rep = (d == T0 || d == A1 || d == A2 || d == (A1 ^ A2)) ? d : (d ^ M);
    const bool flip = (d & HB) != 0;
    float sD = sg[rep];
    float ss = (low != flip) ? -sD : sD;
    an[d] = fmaf(cg[rep], ar[d], ss * ar[d ^ M]);
    pn[d] = fmaf(cg[rep], pr[d], ss * pr[d ^ M]);
  }
#pragma unroll
  for (int d = 0; d < 8; ++d) pr[d] = pn[d];
  // col update: A <- A J  (own pair's rotation; partner col via shuffle)
  float scol = low ? -s : s;
  float aoth[8];
#pragma unroll
  for (int d = 0; d < 8; ++d) aoth[d] = sx<M>(an[d ^ M]);
#pragma unroll
  for (int d = 0; d < 8; ++d) ar[d] = fmaf(c, an[d], scol * aoth[d]);
}

// After sweeps: produce u[i] = U[i][e] (column e of U, absolute row index),
// identical to the old scheme's xperm8(u,e) output.
// pt[d] = sx<d>(pr[d]) = P[e][e^d]; xperm8 -> pt[j] = P[e][j] = U[j][e].
__device__ __forceinline__ void jacobi8rel(float ar[8], float u[8], const int e) {
  float pr[8];
#pragma unroll
  for (int i = 0; i < 8; ++i) pr[i] = (i == 0) ? 1.f : 0.f;  // P = I (relative)
#pragma unroll 1
  for (int sweep = 0; sweep < NSWEEP; ++sweep) {
    jstage<1>(ar, pr, e);
    jstage<2>(ar, pr, e);
    jstage<3>(ar, pr, e);
    jstage<4>(ar, pr, e);
    jstage<5>(ar, pr, e);
    jstage<6>(ar, pr, e);
    jstage<7>(ar, pr, e);
  }
  u[0] = pr[0];
  u[1] = sx<1>(pr[1]);
  u[2] = sx<2>(pr[2]);
  u[3] = sx<3>(pr[3]);
  u[4] = sx<4>(pr[4]);
  u[5] = sx<5>(pr[5]);
  u[6] = sx<6>(pr[6]);
  u[7] = sx<7>(pr[7]);
  xperm8(u, e);   // u[i] = U[i][e]
}

// ---------------- fused kernel: 1 wave = 8 batches, A phase then B phase ----------------
__global__ __launch_bounds__(64) void spdnet_kernel(
    const float* __restrict__ X, const float* __restrict__ w1,
    const float* __restrict__ w2, const float* __restrict__ fc,
    float* __restrict__ out) {
  __shared__ __align__(16) float w1s[C_DIM * 8];  // 496
  __shared__ float Ys[C_DIM * YSTR];              // padded stride 9
  __shared__ float M1s[8 * 64];                   // 8 batches' M1
  __shared__ __align__(16) float Wbuf[8 * WSTRIDE];
  __shared__ float lwbuf[64];
  __shared__ float w2s[64];
  __shared__ float fcs[128];
  const int lane = threadIdx.x;
  const int b0 = blockIdx.x * 8;

  w2s[lane] = w2[lane];
  fcs[lane] = fc[lane];
  fcs[lane + 64] = fc[lane + 64];
  if (lane < C_DIM) {
    *(float4*)(w1s + lane * 8)     = *(const float4*)(w1 + lane * 8);
    *(float4*)(w1s + lane * 8 + 4) = *(const float4*)(w1 + lane * 8 + 4);
  }
  __syncthreads();

  // ---- A phase: M1[g] = w1^T X[b0+g] w1, g = 0..7 serial, per-lane rows ----
#pragma unroll 1
  for (int g = 0; g < 8; ++g) {
    if (lane < C_DIM) {
      // my X row -> registers (31 x float2, 8B-aligned: 248*c % 8 == 0)
      float xr[C_DIM];
      const float* row = X + (size_t)(b0 + g) * CC + lane * C_DIM;
#pragma unroll
      for (int k = 0; k < 31; ++k) {
        float2 t = *(const float2*)(row + 2 * k);
        xr[2 * k] = t.x;
        xr[2 * k + 1] = t.y;
      }
      // Y[c][e] = sum_d X[c][d] * w1[d][e] ; w1s reads wave-uniform broadcast
      float a0=0.f,a1=0.f,a2=0.f,a3=0.f,a4=0.f,a5=0.f,a6=0.f,a7=0.f;
#pragma unroll
      for (int d = 0; d < C_DIM; ++d) {
        float x = xr[d];
        float4 wA = *(const float4*)(w1s + d * 8);
        float4 wB = *(const float4*)(w1s + d * 8 + 4);
        a0 = fmaf(x, wA.x, a0); a1 = fmaf(x, wA.y, a1);
        a2 = fmaf(x, wA.z, a2); a3 = fmaf(x, wA.w, a3);
        a4 = fmaf(x, wB.x, a4); a5 = fmaf(x, wB.y, a5);
        a6 = fmaf(x, wB.z, a6); a7 = fmaf(x, wB.w, a7);
      }
      float* yr = Ys + lane * YSTR;
      yr[0]=a0; yr[1]=a1; yr[2]=a2; yr[3]=a3;
      yr[4]=a4; yr[5]=a5; yr[6]=a6; yr[7]=a7;
    }
    __syncthreads();
    // M1[a][e] = sum_c w1[c][a] * Y[c][e] ; lane = (a<<3)|e
    {
      const int a = lane >> 3, e = lane & 7;
      float s = 0.f;
#pragma unroll
      for (int c = 0; c < C_DIM; ++c)
        s = fmaf(w1s[c * 8 + a], Ys[c * YSTR + e], s);
      M1s[g * 64 + lane] = s;
    }
    __syncthreads();
  }

  // ---- B phase: eig pipeline, 8 lanes per batch ----
  const int e = lane & 7;
  const int g = lane >> 3;
  float a[8], u[8], v[8], m2[8];
  float* Wg = &Wbuf[g * WSTRIDE];

  // row e of symmetric M1 (= column e) from LDS
#pragma unroll
  for (int j = 0; j < 8; ++j) a[j] = M1s[g * 64 + e * 8 + j];

  // ---- eig 1 ----
  xperm8(a, e);                 // absolute row -> relative column
  jacobi8rel(a, u, e);          // u[i] = U[i][e]
  float lam = a[0];             // own eigenvalue (rel slot 0)
  float sw = sqrtf(fmaxf(lam, EPSV));
  // row e of V = U^T w2, scaled by sqrt(clamped eig)
#pragma unroll
  for (int j = 0; j < 8; ++j) v[j] = 0.f;
#pragma unroll
  for (int i = 0; i < 8; ++i)
#pragma unroll
    for (int j = 0; j < 8; ++j) v[j] = fmaf(u[i], w2s[i * 8 + j], v[j]);
#pragma unroll
  for (int j = 0; j < 8; ++j) Wg[e * 8 + j] = v[j] * sw;
  __syncthreads();
  // M2 column e: m2[i] = sum_k W[k][i] * W[k][e]
  {
    float wcol[8];
#pragma unroll
    for (int k = 0; k < 8; ++k) wcol[k] = Wg[k * 8 + e];
#pragma unroll
    for (int i = 0; i < 8; ++i) m2[i] = 0.f;
#pragma unroll
    for (int k = 0; k < 8; ++k) {
      float4 q0 = *(const float4*)&Wg[k * 8 + 0];
      float4 q1 = *(const float4*)&Wg[k * 8 + 4];
      m2[0] = fmaf(q0.x, wcol[k], m2[0]); m2[1] = fmaf(q0.y, wcol[k], m2[1]);
      m2[2] = fmaf(q0.z, wcol[k], m2[2]); m2[3] = fmaf(q0.w, wcol[k], m2[3]);
      m2[4] = fmaf(q1.x, wcol[k], m2[4]); m2[5] = fmaf(q1.y, wcol[k], m2[5]);
      m2[6] = fmaf(q1.z, wcol[k], m2[6]); m2[7] = fmaf(q1.w, wcol[k], m2[7]);
    }
  }
  __syncthreads();  // Wbuf reads done before reuse

  // ---- eig 2 + fused rec+logm ----
  xperm8(m2, e);
  jacobi8rel(m2, u, e);
  float lw = logf(fmaxf(m2[0], EPSV));
#pragma unroll
  for (int i = 0; i < 8; ++i) Wg[e * 8 + i] = u[i];
  lwbuf[g * 8 + e] = lw;
  __syncthreads();
  // feat column e: fcol[i] = sum_k lw_k * T[k][i] * T[k][e]
  {
    float mk[8];
#pragma unroll
    for (int k = 0; k < 8; ++k) mk[k] = lwbuf[g * 8 + k] * Wg[k * 8 + e];
    float fcol[8];
#pragma unroll
    for (int i = 0; i < 8; ++i) fcol[i] = 0.f;
#pragma unroll
    for (int k = 0; k < 8; ++k) {
      float4 q0 = *(const float4*)&Wg[k * 8 + 0];
      float4 q1 = *(const float4*)&Wg[k * 8 + 4];
      fcol[0] = fmaf(q0.x, mk[k], fcol[0]); fcol[1] = fmaf(q0.y, mk[k], fcol[1]);
      fcol[2] = fmaf(q0.z, mk[k], fcol[2]); fcol[3] = fmaf(q0.w, mk[k], fcol[3]);
      fcol[4] = fmaf(q1.x, mk[k], fcol[4]); fcol[5] = fmaf(q1.y, mk[k], fcol[5]);
      fcol[6] = fmaf(q1.z, mk[k], fcol[6]); fcol[7] = fmaf(q1.w, mk[k], fcol[7]);
    }
    float l0 = 0.f, l1 = 0.f;
    const int b = b0 + g;
    float* featg = out + 2 * (size_t)B_TOTAL + (size_t)b * 64;
#pragma unroll
    for (int i = 0; i < 8; ++i) {
      featg[i * 8 + e] = fcol[i];
      l0 = fmaf(fcol[i], fcs[(i * 8 + e) * 2 + 0], l0);
      l1 = fmaf(fcol[i], fcs[(i * 8 + e) * 2 + 1], l1);
    }
    l0 += sx<1>(l0); l0 += sx<2>(l0); l0 += sx<4>(l0);
    l1 += sx<1>(l1); l1 += sx<2>(l1); l1 += sx<4>(l1);
    float mx = fmaxf(l0, l1);
    float lse = mx + logf(expf(l0 - mx) + expf(l1 - mx));
    if (e < 2) out[(size_t)b * 2 + e] = (e ? l1 : l0) - lse;
  }
}

extern "C" void kernel_launch(void* const* d_in, const int* in_sizes, int n_in,
                              void* d_out, int out_size, void* d_ws, size_t ws_size,
                              hipStream_t stream) {
  const float* X  = (const float*)d_in[0];   // [8192,62,62]
  const float* w1 = (const float*)d_in[1];   // [62,8]
  const float* w2 = (const float*)d_in[2];   // [8,8]
  const float* fc = (const float*)d_in[3];   // [64,2]
  float* out = (float*)d_out;                // [8192*2] ++ [8192*64]

  spdnet_kernel<<<B_TOTAL / 8, 64, 0, stream>>>(X, w1, w2, fc, out);
}

// Round 13
// 48.741 us; speedup vs baseline: 9.2680x; 1.1611x over previous
//
#include <hip/hip_runtime.h>
#include <math.h>

#define B_TOTAL 8192
#define C_DIM 62
#define CC (C_DIM * C_DIM)   // 3844 floats
#define EPSV 1e-4f
#define NSWEEP 4
#define WSTRIDE 72           // per-group exchange stride
#define YSTR 9               // Ys stride: gcd(9,32)=1 -> conflict-free writes

// ---------- cross-lane xor-shuffle: DPP (VALU) for masks 1..3, swizzle 4..7 ----------
template<int M> __device__ __forceinline__ float sx(float x) {
  int xi = __builtin_bit_cast(int, x);
  int r;
  if constexpr (M == 1)      r = __builtin_amdgcn_update_dpp(xi, xi, 0xB1, 0xF, 0xF, false);
  else if constexpr (M == 2) r = __builtin_amdgcn_update_dpp(xi, xi, 0x4E, 0xF, 0xF, false);
  else if constexpr (M == 3) r = __builtin_amdgcn_update_dpp(xi, xi, 0x1B, 0xF, 0xF, false);
  else                       r = __builtin_amdgcn_ds_swizzle(xi, (M << 10) | 0x1F);
  return __builtin_bit_cast(float, r);
}

// in-register xor-permute: r[j] <- r[j ^ e]   (24 cndmask)
__device__ __forceinline__ void xperm8(float r[8], const int e) {
  const bool b0 = (e & 1) != 0, b1 = (e & 2) != 0, b2 = (e & 4) != 0;
  float t0[8], t1[8];
#pragma unroll
  for (int j = 0; j < 8; ++j) t0[j] = b0 ? r[j ^ 1] : r[j];
#pragma unroll
  for (int j = 0; j < 8; ++j) t1[j] = b1 ? t0[j ^ 2] : t0[j];
#pragma unroll
  for (int j = 0; j < 8; ++j) r[j] = b2 ? t1[j ^ 4] : t1[j];
}

// ---------- one tournament stage, XOR-relative storage ----------
// lane e stores ar[d] = A[e^d][e]  and  pr[d] = P[e^d][e] where P = U^T.
template<int M>
__device__ __forceinline__ void jstage(float ar[8], float pr[8], const int e) {
  constexpr int HB = (M >= 4) ? 4 : ((M >= 2) ? 2 : 1);  // highest bit of M
  constexpr int A1 = (M == 1) ? 2 : 1;                   // transversal masks
  constexpr int A2 = (M <= 3) ? 4 : 2;
  const bool low = (e & HB) == 0;      // is e the min of its pair
  float d_oth = sx<M>(ar[0]);
  float o_oth = sx<M>(ar[M]);
  float apq = 0.5f * (ar[M] + o_oth);  // symmetrized: both lanes identical
  float app = low ? ar[0] : d_oth;
  float aqq = low ? d_oth : ar[0];
  float taun = aqq - app;
  float den = fabsf(taun) + sqrtf(fmaf(taun, taun, 4.f * apq * apq)) + 1e-38f;
  float t = (2.f * apq) * copysignf(1.f, taun) * __builtin_amdgcn_rcpf(den);
  float c = rsqrtf(fmaf(t, t, 1.f));
  float s = t * c;                      // canonical (p=min, q=max) rotation
  // allgather canonical (c,s) of all 4 pairs into transversal slots
  float cg[8], sg[8];
  cg[0] = c;  sg[0] = s;
  cg[A1] = sx<A1>(c);  sg[A1] = sx<A1>(s);
  cg[A2] = sx<A2>(c);  sg[A2] = sx<A2>(s);
  cg[A1 ^ A2] = sx<A2>(cg[A1]);  sg[A1 ^ A2] = sx<A2>(sg[A1]);
  // row update: A <- J^T A  and  P <- J^T P  (same pairs, same coeffs)
  float an[8], pn[8];
#pragma unroll
  for (int d = 0; d < 8; ++d) {
    constexpr int T0 = 0;
    const int rep = (d == T0 || d == A1 || d == A2 || d == (A1 ^ A2)) ? d : (d ^ M);
    const bool flip = (d & HB) != 0;
    float sD = sg[rep];
    float ss = (low != flip) ? -sD : sD;
    an[d] = fmaf(cg[rep], ar[d], ss * ar[d ^ M]);
    pn[d] = fmaf(cg[rep], pr[d], ss * pr[d ^ M]);
  }
#pragma unroll
  for (int d = 0; d < 8; ++d) pr[d] = pn[d];
  // col update: A <- A J  (own pair's rotation; partner col via shuffle)
  float scol = low ? -s : s;
  float aoth[8];
#pragma unroll
  for (int d = 0; d < 8; ++d) aoth[d] = sx<M>(an[d ^ M]);
#pragma unroll
  for (int d = 0; d < 8; ++d) ar[d] = fmaf(c, an[d], scol * aoth[d]);
}

// After sweeps: u[i] = U[i][e] via 7-shuffle transpose + xperm8.
__device__ __forceinline__ void jacobi8rel(float ar[8], float u[8], const int e) {
  float pr[8];
#pragma unroll
  for (int i = 0; i < 8; ++i) pr[i] = (i == 0) ? 1.f : 0.f;  // P = I (relative)
#pragma unroll 1
  for (int sweep = 0; sweep < NSWEEP; ++sweep) {
    jstage<1>(ar, pr, e);
    jstage<2>(ar, pr, e);
    jstage<3>(ar, pr, e);
    jstage<4>(ar, pr, e);
    jstage<5>(ar, pr, e);
    jstage<6>(ar, pr, e);
    jstage<7>(ar, pr, e);
  }
  u[0] = pr[0];
  u[1] = sx<1>(pr[1]);
  u[2] = sx<2>(pr[2]);
  u[3] = sx<3>(pr[3]);
  u[4] = sx<4>(pr[4]);
  u[5] = sx<5>(pr[5]);
  u[6] = sx<6>(pr[6]);
  u[7] = sx<7>(pr[7]);
  xperm8(u, e);   // u[i] = U[i][e]
}

// ---------------- fused kernel: 1 wave = 8 batches, A phase then B phase ----------------
__global__ __launch_bounds__(64) void spdnet_kernel(
    const float* __restrict__ X, const float* __restrict__ w1,
    const float* __restrict__ w2, const float* __restrict__ fc,
    float* __restrict__ out) {
  __shared__ __align__(16) float w1s[C_DIM * 8];  // 496
  __shared__ float Ys[C_DIM * YSTR];              // padded stride 9
  __shared__ float M1s[8 * 64];                   // 8 batches' M1
  __shared__ __align__(16) float Wbuf[8 * WSTRIDE];
  __shared__ float lwbuf[64];
  __shared__ float w2s[64];
  __shared__ float fcs[128];
  const int lane = threadIdx.x;
  const int b0 = blockIdx.x * 8;

  w2s[lane] = w2[lane];
  fcs[lane] = fc[lane];
  fcs[lane + 64] = fc[lane + 64];
  if (lane < C_DIM) {
    *(float4*)(w1s + lane * 8)     = *(const float4*)(w1 + lane * 8);
    *(float4*)(w1s + lane * 8 + 4) = *(const float4*)(w1 + lane * 8 + 4);
  }

  // ---- A phase: M1[g] = w1^T X[b0+g] w1, ping-pong register prefetch ----
  float xrA[C_DIM], xrB[C_DIM];
  // prefetch batch 0 (before the weights barrier: loads fly during it)
  if (lane < C_DIM) {
    const float* row = X + (size_t)b0 * CC + lane * C_DIM;
#pragma unroll
    for (int k = 0; k < 31; ++k) {
      float2 t = *(const float2*)(row + 2 * k);
      xrA[2 * k] = t.x; xrA[2 * k + 1] = t.y;
    }
  }
  __syncthreads();

  auto loadrow = [&](float* r, int g) {
    if (lane < C_DIM) {
      const float* row = X + (size_t)(b0 + g) * CC + lane * C_DIM;
#pragma unroll
      for (int k = 0; k < 31; ++k) {
        float2 t = *(const float2*)(row + 2 * k);
        r[2 * k] = t.x; r[2 * k + 1] = t.y;
      }
    }
  };
  auto computeA = [&](const float* xr, int g) {
    if (lane < C_DIM) {
      float a0=0.f,a1=0.f,a2=0.f,a3=0.f,a4=0.f,a5=0.f,a6=0.f,a7=0.f;
#pragma unroll
      for (int d = 0; d < C_DIM; ++d) {
        float x = xr[d];
        float4 wA = *(const float4*)(w1s + d * 8);
        float4 wB = *(const float4*)(w1s + d * 8 + 4);
        a0 = fmaf(x, wA.x, a0); a1 = fmaf(x, wA.y, a1);
        a2 = fmaf(x, wA.z, a2); a3 = fmaf(x, wA.w, a3);
        a4 = fmaf(x, wB.x, a4); a5 = fmaf(x, wB.y, a5);
        a6 = fmaf(x, wB.z, a6); a7 = fmaf(x, wB.w, a7);
      }
      float* yr = Ys + lane * YSTR;
      yr[0]=a0; yr[1]=a1; yr[2]=a2; yr[3]=a3;
      yr[4]=a4; yr[5]=a5; yr[6]=a6; yr[7]=a7;
    }
    __syncthreads();
    {
      const int a_ = lane >> 3, e_ = lane & 7;
      float s = 0.f;
#pragma unroll
      for (int c = 0; c < C_DIM; ++c)
        s = fmaf(w1s[c * 8 + a_], Ys[c * YSTR + e_], s);
      M1s[g * 64 + lane] = s;
    }
    __syncthreads();
  };

#pragma unroll 1
  for (int g = 0; g < 8; g += 2) {
    loadrow(xrB, g + 1);               // prefetch g+1; flies under computeA(g)
    computeA(xrA, g);
    if (g + 2 < 8) loadrow(xrA, g + 2); // prefetch g+2; flies under computeA(g+1)
    computeA(xrB, g + 1);
  }

  // ---- B phase: eig pipeline, 8 lanes per batch ----
  const int e = lane & 7;
  const int g = lane >> 3;
  float a[8], u[8], v[8], m2[8];
  float* Wg = &Wbuf[g * WSTRIDE];

  // row e of symmetric M1 (= column e) from LDS
#pragma unroll
  for (int j = 0; j < 8; ++j) a[j] = M1s[g * 64 + e * 8 + j];

  // ---- eig 1 ----
  xperm8(a, e);                 // absolute row -> relative column
  jacobi8rel(a, u, e);          // u[i] = U[i][e]
  float lam = a[0];             // own eigenvalue (rel slot 0)
  float sw = sqrtf(fmaxf(lam, EPSV));
  // row e of V = U^T w2, scaled by sqrt(clamped eig)
#pragma unroll
  for (int j = 0; j < 8; ++j) v[j] = 0.f;
#pragma unroll
  for (int i = 0; i < 8; ++i)
#pragma unroll
    for (int j = 0; j < 8; ++j) v[j] = fmaf(u[i], w2s[i * 8 + j], v[j]);
#pragma unroll
  for (int j = 0; j < 8; ++j) Wg[e * 8 + j] = v[j] * sw;
  __syncthreads();
  // M2 column e: m2[i] = sum_k W[k][i] * W[k][e]
  {
    float wcol[8];
#pragma unroll
    for (int k = 0; k < 8; ++k) wcol[k] = Wg[k * 8 + e];
#pragma unroll
    for (int i = 0; i < 8; ++i) m2[i] = 0.f;
#pragma unroll
    for (int k = 0; k < 8; ++k) {
      float4 q0 = *(const float4*)&Wg[k * 8 + 0];
      float4 q1 = *(const float4*)&Wg[k * 8 + 4];
      m2[0] = fmaf(q0.x, wcol[k], m2[0]); m2[1] = fmaf(q0.y, wcol[k], m2[1]);
      m2[2] = fmaf(q0.z, wcol[k], m2[2]); m2[3] = fmaf(q0.w, wcol[k], m2[3]);
      m2[4] = fmaf(q1.x, wcol[k], m2[4]); m2[5] = fmaf(q1.y, wcol[k], m2[5]);
      m2[6] = fmaf(q1.z, wcol[k], m2[6]); m2[7] = fmaf(q1.w, wcol[k], m2[7]);
    }
  }
  __syncthreads();  // Wbuf reads done before reuse

  // ---- eig 2 + fused rec+logm ----
  xperm8(m2, e);
  jacobi8rel(m2, u, e);
  float lw = logf(fmaxf(m2[0], EPSV));
#pragma unroll
  for (int i = 0; i < 8; ++i) Wg[e * 8 + i] = u[i];
  lwbuf[g * 8 + e] = lw;
  __syncthreads();
  // feat column e: fcol[i] = sum_k lw_k * T[k][i] * T[k][e]
  {
    float mk[8];
#pragma unroll
    for (int k = 0; k < 8; ++k) mk[k] = lwbuf[g * 8 + k] * Wg[k * 8 + e];
    float fcol[8];
#pragma unroll
    for (int i = 0; i < 8; ++i) fcol[i] = 0.f;
#pragma unroll
    for (int k = 0; k < 8; ++k) {
      float4 q0 = *(const float4*)&Wg[k * 8 + 0];
      float4 q1 = *(const float4*)&Wg[k * 8 + 4];
      fcol[0] = fmaf(q0.x, mk[k], fcol[0]); fcol[1] = fmaf(q0.y, mk[k], fcol[1]);
      fcol[2] = fmaf(q0.z, mk[k], fcol[2]); fcol[3] = fmaf(q0.w, mk[k], fcol[3]);
      fcol[4] = fmaf(q1.x, mk[k], fcol[4]); fcol[5] = fmaf(q1.y, mk[k], fcol[5]);
      fcol[6] = fmaf(q1.z, mk[k], fcol[6]); fcol[7] = fmaf(q1.w, mk[k], fcol[7]);
    }
    float l0 = 0.f, l1 = 0.f;
    const int b = b0 + g;
    float* featg = out + 2 * (size_t)B_TOTAL + (size_t)b * 64;
#pragma unroll
    for (int i = 0; i < 8; ++i) {
      featg[i * 8 + e] = fcol[i];
      l0 = fmaf(fcol[i], fcs[(i * 8 + e) * 2 + 0], l0);
      l1 = fmaf(fcol[i], fcs[(i * 8 + e) * 2 + 1], l1);
    }
    l0 += sx<1>(l0); l0 += sx<2>(l0); l0 += sx<4>(l0);
    l1 += sx<1>(l1); l1 += sx<2>(l1); l1 += sx<4>(l1);
    float mx = fmaxf(l0, l1);
    float lse = mx + logf(expf(l0 - mx) + expf(l1 - mx));
    if (e < 2) out[(size_t)b * 2 + e] = (e ? l1 : l0) - lse;
  }
}

extern "C" void kernel_launch(void* const* d_in, const int* in_sizes, int n_in,
                              void* d_out, int out_size, void* d_ws, size_t ws_size,
                              hipStream_t stream) {
  const float* X  = (const float*)d_in[0];   // [8192,62,62]
  const float* w1 = (const float*)d_in[1];   // [62,8]
  const float* w2 = (const float*)d_in[2];   // [8,8]
  const float* fc = (const float*)d_in[3];   // [64,2]
  float* out = (float*)d_out;                // [8192*2] ++ [8192*64]

  spdnet_kernel<<<B_TOTAL / 8, 64, 0, stream>>>(X, w1, w2, fc, out);
}